// Round 5
// baseline (175.091 us; speedup 1.0000x reference)
//
#include <hip/hip_runtime.h>
#include <math.h>

#define FREQ_DIM 256
#define TDIM 512
#define MODC 352
#define EPS 1e-5f

__device__ __forceinline__ float silu_f(float x) {
    return x / (1.0f + expf(-x));
}

// One MLP layer for R rows resident in LDS.
// 512 threads = 128 col-groups (4 cols each, float4 w loads) x KS=4 k-slices.
// Split-k partials reduced via s_acc in LDS. Ends with __syncthreads().
template <int K, int NC, int R, bool POST_SILU, bool TO_GLOBAL>
__device__ __forceinline__ void stage(const float* s_in,              // [R][TDIM]
                                      const float* __restrict__ w,    // [K][NC]
                                      const float* __restrict__ bias, // [NC]
                                      float* outp,                    // LDS [R][TDIM] or global [R][NC]
                                      float* s_acc,                   // [KS][R][512]
                                      int tid) {
    constexpr int KS = 4, KC = K / KS;
    int c4 = tid & 127;
    int ks = tid >> 7;                  // wave-uniform (128 | 64)
    int j0 = 4 * c4;
    int jj = (j0 <= NC - 4) ? j0 : (NC - 4);   // clamp for NC=352 tail (aligned)
    const float* wp = w + jj;

    float4 acc[R];
#pragma unroll
    for (int r = 0; r < R; ++r) acc[r] = make_float4(0.f, 0.f, 0.f, 0.f);

    int kbeg = ks * KC, kend = kbeg + KC;

    // software-pipelined: wn holds next chunk's 4 float4 weight rows
    float4 wn[4];
#pragma unroll
    for (int kk = 0; kk < 4; ++kk) wn[kk] = *(const float4*)(wp + (size_t)(kbeg + kk) * NC);

    for (int k = kbeg; k < kend; k += 4) {
        float4 wc[4];
#pragma unroll
        for (int kk = 0; kk < 4; ++kk) wc[kk] = wn[kk];
        int kn = (k + 4 < kend) ? (k + 4) : k;   // last iter: redundant reload
#pragma unroll
        for (int kk = 0; kk < 4; ++kk) wn[kk] = *(const float4*)(wp + (size_t)(kn + kk) * NC);

        float4 sa[R];
#pragma unroll
        for (int r = 0; r < R; ++r) sa[r] = *(const float4*)(s_in + r * TDIM + k);

#pragma unroll
        for (int kk = 0; kk < 4; ++kk) {
#pragma unroll
            for (int r = 0; r < R; ++r) {
                float s = (&sa[r].x)[kk];
                acc[r].x += s * wc[kk].x;
                acc[r].y += s * wc[kk].y;
                acc[r].z += s * wc[kk].z;
                acc[r].w += s * wc[kk].w;
            }
        }
    }

    // partials at UNCLAMPED j0 (clamped threads write junk to cols >= NC, never read)
    float* pa = s_acc + (size_t)(ks * R) * 512;
#pragma unroll
    for (int r = 0; r < R; ++r) *(float4*)(pa + r * 512 + j0) = acc[r];
    __syncthreads();

    for (int o = tid; o < R * NC; o += 512) {
        int r = o / NC, c = o - r * NC;
        float v = s_acc[(0 * R + r) * 512 + c] + s_acc[(1 * R + r) * 512 + c] +
                  s_acc[(2 * R + r) * 512 + c] + s_acc[(3 * R + r) * 512 + c];
        v += bias[c];
        if (POST_SILU) v = silu_f(v);
        if (TO_GLOBAL) outp[(size_t)r * NC + c] = v;
        else           outp[r * TDIM + c] = v;
    }
    __syncthreads();
}

// Fused time-embedding MLP: emb -> silu(.@w1+b1) -> silu(.@w2+b2) -> .@wm+bm
// (silu of t2 folded into stage-2's write per reference: mod = silu(t_emb)@wm+bm)
template <int R>
__global__ __launch_bounds__(512) void k_mlp(const float* __restrict__ t,
                                             const float* __restrict__ w1, const float* __restrict__ b1,
                                             const float* __restrict__ w2, const float* __restrict__ b2,
                                             const float* __restrict__ wm, const float* __restrict__ bm,
                                             float* __restrict__ mb) {
    __shared__ __align__(16) float s_x[R * TDIM];      // 8 KB
    __shared__ __align__(16) float s_y[R * TDIM];      // 8 KB
    __shared__ __align__(16) float s_acc[4 * R * 512]; // 32 KB
    __shared__ float s_t[R];

    int tid = threadIdx.x;
    int row0 = blockIdx.x * R;

    if (tid < R) s_t[tid] = t[row0 + tid];
    __syncthreads();

    // timestep embedding into s_x[r][0..255]
    const float lm = 9.210340371976184f;   // ln(10000)
    for (int idx = tid; idx < R * FREQ_DIM; idx += 512) {
        int r = idx >> 8, j = idx & 255;
        int h = j & 127;
        float freq = expf(-lm * (float)h * (1.0f / 128.0f));
        float arg = s_t[r] * freq;
        s_x[r * TDIM + j] = (j < 128) ? cosf(arg) : sinf(arg);
    }
    __syncthreads();

    stage<FREQ_DIM, TDIM, R, true,  false>(s_x, w1, b1, s_y, s_acc, tid);
    stage<TDIM,     TDIM, R, true,  false>(s_y, w2, b2, s_x, s_acc, tid);
    stage<TDIM,     MODC, R, false, true >(s_x, wm, bm, mb + (size_t)row0 * MODC, s_acc, tid);
}

// One wave (64 lanes) per node. Row = 480 f32 = 120 float4.
// float4 idx:  0..31 -> seg0 (layernorm, floats 0..127)
//             32..79 -> seg1 (floats 128..319, 192 elems)
//             80..119-> seg2 (floats 320..479, 160 elems)
__global__ __launch_bounds__(256) void k_main(const float* __restrict__ x,
                                              const int* __restrict__ batch,
                                              const float* __restrict__ mod,
                                              float* __restrict__ out, int N) {
    int node = blockIdx.x * 4 + (threadIdx.x >> 6);
    if (node >= N) return;
    int lane = threadIdx.x & 63;

    const float4* rp = (const float4*)(x + (size_t)node * 480);
    float4 a = rp[lane];                         // f4 idx lane (0..63)
    float4 c = make_float4(0.f, 0.f, 0.f, 0.f);
    if (lane < 56) c = rp[64 + lane];            // f4 idx 64..119

    float s0 = 0.f, q0 = 0.f, q1 = 0.f, q2 = 0.f;
    float da = a.x * a.x + a.y * a.y + a.z * a.z + a.w * a.w;
    if (lane < 32) { s0 = a.x + a.y + a.z + a.w; q0 = da; }
    else           { q1 = da; }
    float dc = c.x * c.x + c.y * c.y + c.z * c.z + c.w * c.w;
    if (lane < 16)      q1 += dc;
    else if (lane < 56) q2 = dc;

#pragma unroll
    for (int m = 1; m < 64; m <<= 1) {
        s0 += __shfl_xor(s0, m, 64);
        q0 += __shfl_xor(q0, m, 64);
        q1 += __shfl_xor(q1, m, 64);
        q2 += __shfl_xor(q2, m, 64);
    }

    int b = batch[node];
    const float* mrow = mod + (size_t)b * MODC;
    float4 m4 = *(const float4*)mrow;            // cols 0..3 (need 0,1,2)

    float mean = s0 * (1.0f / 128.0f);
    float var  = q0 * (1.0f / 128.0f) - mean * mean;
    float r0 = rsqrtf(var + EPS) * (1.0f + m4.x);
    float r1 = rsqrtf(q1 * (1.0f / 192.0f) + EPS) * (1.0f + m4.y);
    float r2 = rsqrtf(q2 * (1.0f / 160.0f) + EPS) * (1.0f + m4.z);

    float4* op = (float4*)(out + (size_t)node * 480);
    float4 o;
    if (lane < 32) {
        float4 sh = *(const float4*)(mrow + 224 + 4 * lane);
        o.x = (a.x - mean) * r0 + sh.x;
        o.y = (a.y - mean) * r0 + sh.y;
        o.z = (a.z - mean) * r0 + sh.z;
        o.w = (a.w - mean) * r0 + sh.w;
    } else {
        o.x = a.x * r1; o.y = a.y * r1; o.z = a.z * r1; o.w = a.w * r1;
    }
    op[lane] = o;
    if (lane < 56) {
        float rr = (lane < 16) ? r1 : r2;
        float4 o2;
        o2.x = c.x * rr; o2.y = c.y * rr; o2.z = c.z * rr; o2.w = c.w * rr;
        op[64 + lane] = o2;
    }
}

extern "C" void kernel_launch(void* const* d_in, const int* in_sizes, int n_in,
                              void* d_out, int out_size, void* d_ws, size_t ws_size,
                              hipStream_t stream) {
    const float* node_input = (const float*)d_in[0];
    const float* t          = (const float*)d_in[1];
    const int*   batch      = (const int*)d_in[2];
    const float* w1         = (const float*)d_in[3];
    const float* b1         = (const float*)d_in[4];
    const float* w2         = (const float*)d_in[5];
    const float* b2         = (const float*)d_in[6];
    const float* wm         = (const float*)d_in[7];
    const float* bm         = (const float*)d_in[8];
    float* out = (float*)d_out;

    int N = in_sizes[0] / 480;   // 100000
    int B = in_sizes[1];         // 1024

    float* mb = (float*)d_ws;    // B*352 f32

    constexpr int R = 4;
    k_mlp<R><<<B / R, 512, 0, stream>>>(t, w1, b1, w2, b2, wm, bm, mb);
    k_main<<<(N + 3) / 4, 256, 0, stream>>>(node_input, batch, mb, out, N);
}